// Round 1
// baseline (29.129 us; speedup 1.0000x reference)
//
#include <hip/hip_runtime.h>

#define NB 16
#define KK 128
#define CC 64

// tanh(x) given e2x = exp(2x):  tanh = 1 - 2/(e2x+1)
__device__ __forceinline__ float tanh_from_e2x(float e2x) {
    return 1.f - 2.f * __builtin_amdgcn_rcpf(e2x + 1.f);
}

// Kernel 1: per row r = n*K+k (one wave each):
//   h      = [t, x_r] @ W_lin + b_lin
//   unary  = tanh(h@W_u1+b_u1)@W_u2 + b_u2
//   A2[r]  = 2*(h @ W_b1[e][0:C]  + b_b1[e])   (receiver/j part, e interleaved)
//   B2[r]  = 2*(h @ W_b1[e][C:2C])             (sender/i part,   e interleaved)
__global__ __launch_bounds__(256) void precompute_kernel(
    const float* __restrict__ t, const float* __restrict__ x,
    const float* __restrict__ W_lin, const float* __restrict__ b_lin,
    const float* __restrict__ W_u1, const float* __restrict__ b_u1,
    const float* __restrict__ W_u2, const float* __restrict__ b_u2,
    const float* __restrict__ W_b1, const float* __restrict__ b_b1,
    float* __restrict__ A2, float* __restrict__ B2, float* __restrict__ unary)
{
    const int tid  = threadIdx.x;
    const int lane = tid & 63;
    const int r    = blockIdx.x * 4 + (tid >> 6);   // row in [0, N*K)

    const float xv = x[r * CC + lane];
    float h = fmaf(t[0], W_lin[lane], b_lin[lane]);
#pragma unroll 8
    for (int k = 0; k < CC; ++k) {
        float xk = __shfl(xv, k);
        h = fmaf(xk, W_lin[(k + 1) * CC + lane], h);
    }

    float u1 = b_u1[lane];
    float a0 = b_b1[lane], a1 = b_b1[CC + lane];
    float bb0 = 0.f, bb1 = 0.f;
#pragma unroll 4
    for (int k = 0; k < CC; ++k) {
        float hk = __shfl(h, k);
        u1  = fmaf(hk, W_u1[k * CC + lane], u1);
        a0  = fmaf(hk, W_b1[k * CC + lane], a0);
        bb0 = fmaf(hk, W_b1[(CC + k) * CC + lane], bb0);
        a1  = fmaf(hk, W_b1[2 * CC * CC + k * CC + lane], a1);
        bb1 = fmaf(hk, W_b1[2 * CC * CC + (CC + k) * CC + lane], bb1);
    }

    float tu = tanh_from_e2x(__expf(2.f * u1));
    float u2 = b_u2[lane];
#pragma unroll 8
    for (int k = 0; k < CC; ++k) {
        float uk = __shfl(tu, k);
        u2 = fmaf(uk, W_u2[k * CC + lane], u2);
    }

    const int idx = r * CC + lane;
    unary[idx] = u2;
    ((float2*)A2)[idx] = make_float2(2.f * a0, 2.f * a1);
    ((float2*)B2)[idx] = make_float2(2.f * bb0, 2.f * bb1);
}

// Kernel 2: block = one n, 4 receiver nodes j (one per wave), both edge types.
//   G[e,h] = sum_i E[n,i,j,e] * tanh(A[e,n,j,h] + B[e,n,i,h])
//   out[n,j,c] = unary + (1/K) * sum_e (G[e]@W_b2[e] + b_b2[e]*sum_i E)
__global__ __launch_bounds__(256) void binary_kernel(
    const float* __restrict__ E, const float* __restrict__ W_b2,
    const float* __restrict__ b_b2, const float* __restrict__ A2,
    const float* __restrict__ B2, const float* __restrict__ unary,
    float* __restrict__ out)
{
    __shared__ float Bs[KK * CC * 2];   // 64 KiB  [i][h][e]
    __shared__ float Es[4 * KK * 2];    //  4 KiB  [w][i][e]
    __shared__ float Gs[4 * CC * 2];    //  2 KiB  [w][h][e]

    const int tid = threadIdx.x;
    const int bid = blockIdx.x;
    const int n   = bid >> 5;           // K/4 = 32 j-groups per n
    const int j0  = (bid & 31) * 4;

    // stage B2[n] (both e): 16384 floats = 4096 float4
    const float4* Bsrc = (const float4*)(B2 + n * KK * CC * 2);
    float4* Bdst = (float4*)Bs;
#pragma unroll
    for (int it = 0; it < 16; ++it) Bdst[tid + it * 256] = Bsrc[tid + it * 256];

    // stage E[n, :, j0..j0+3, :] as float2 (both e contiguous)
    const float2* E2 = (const float2*)E;
    float2* Es2 = (float2*)Es;
#pragma unroll
    for (int it = 0; it < 2; ++it) {
        int v = tid + it * 256;         // [0,512)
        int wv = v >> 7, i = v & 127;
        Es2[wv * KK + i] = E2[(n * KK + i) * KK + (j0 + wv)];
    }
    __syncthreads();

    const int lane = tid & 63;
    const int w    = tid >> 6;
    const int r    = n * KK + j0 + w;

    const float2 a2 = ((const float2*)A2)[r * CC + lane];
    const float2* BsRow = (const float2*)Bs;
    const float2* EsW   = ((const float2*)Es) + w * KK;

    float G0 = 0.f, G1 = 0.f;
#pragma unroll 8
    for (int i = 0; i < KK; ++i) {
        float2 bb = BsRow[i * CC + lane];
        float2 wg = EsW[i];
        float t0 = tanh_from_e2x(__expf(a2.x + bb.x));   // a2, bb pre-doubled
        float t1 = tanh_from_e2x(__expf(a2.y + bb.y));
        G0 = fmaf(wg.x, t0, G0);
        G1 = fmaf(wg.y, t1, G1);
    }
    ((float2*)Gs)[w * CC + lane] = make_float2(G0, G1);

    // S[e] = sum_i E (butterfly reduce; every lane needs it)
    float2 sv0 = EsW[lane], sv1 = EsW[CC + lane];
    float S0 = sv0.x + sv1.x, S1 = sv0.y + sv1.y;
#pragma unroll
    for (int m = 32; m; m >>= 1) {
        S0 += __shfl_xor(S0, m);
        S1 += __shfl_xor(S1, m);
    }
    __syncthreads();

    // epilogue matvec: lane = output channel c
    float acc = 0.f;
    const float2* GsW = ((const float2*)Gs) + w * CC;
#pragma unroll 8
    for (int hh = 0; hh < CC; ++hh) {
        float2 g = GsW[hh];
        acc = fmaf(g.x, W_b2[hh * CC + lane], acc);
        acc = fmaf(g.y, W_b2[CC * CC + hh * CC + lane], acc);
    }
    acc += b_b2[lane] * S0 + b_b2[CC + lane] * S1;

    out[r * CC + lane] = unary[r * CC + lane] + acc * (1.f / 128.f);
}

extern "C" void kernel_launch(void* const* d_in, const int* in_sizes, int n_in,
                              void* d_out, int out_size, void* d_ws, size_t ws_size,
                              hipStream_t stream) {
    const float* t     = (const float*)d_in[0];
    const float* x     = (const float*)d_in[1];
    const float* E     = (const float*)d_in[2];
    const float* W_lin = (const float*)d_in[3];
    const float* b_lin = (const float*)d_in[4];
    const float* W_u1  = (const float*)d_in[5];
    const float* b_u1  = (const float*)d_in[6];
    const float* W_u2  = (const float*)d_in[7];
    const float* b_u2  = (const float*)d_in[8];
    const float* W_b1  = (const float*)d_in[9];
    const float* b_b1  = (const float*)d_in[10];
    const float* W_b2  = (const float*)d_in[11];
    const float* b_b2  = (const float*)d_in[12];
    float* out = (float*)d_out;

    float* ws    = (float*)d_ws;
    float* A2    = ws;                 // 2*N*K*C floats (e-interleaved)
    float* B2    = ws + 2 * NB * KK * CC;
    float* unary = ws + 4 * NB * KK * CC;

    precompute_kernel<<<NB * KK / 4, 256, 0, stream>>>(
        t, x, W_lin, b_lin, W_u1, b_u1, W_u2, b_u2, W_b1, b_b1, A2, B2, unary);
    binary_kernel<<<NB * (KK / 4), 256, 0, stream>>>(
        E, W_b2, b_b2, A2, B2, unary, out);
}